// Round 2
// baseline (16.119 us; speedup 1.0000x reference)
//
#include <hip/hip_runtime.h>

// FastSpeech2 hard duration-based frame->token averaging.
// R10: move the divergent frame gather off the VMEM pipe onto LDS.
//  - Phase A: async coalesced global->LDS staging of first 512 quads
//    (global_load_lds width=16), issued BEFORE the duration scan so HBM
//    latency hides under it.
//  - Phase B: after the scan we know total = sum(dur); stage the remaining
//    quads up to Qneed = ceil(min(total, flen)/4) (block-uniform branch).
//  - Gather: 9x ds_read_b128 per thread from LDS (banked, divergence-tolerant)
//    instead of 9x global_load_dwordx4 with 64 distinct lines/instr (the
//    R8/R9 bottleneck: ~147K wave-gathers x 64 line-requests ~ 15 us of L1
//    serialization; R9's L1-hot redirect nulling at 14.07us confirmed the
//    cost is per-address processing, not cacheability).
//  - VALU trim: peeled j=0 quad (only one where p>=si can fail), acc0
//    predicate reduced to (p<mi), v_rcp_f32 divides.
// Output = [B*TT token_scalar | B duration_len(float)].

namespace {
constexpr int TT = 1024;   // tokens per row
constexpr int TF = 8192;   // frames per row
constexpr int NT = 512;    // threads per block (8 waves)
constexpr int NW = NT / 64;
constexpr int QROW = TF / 4;     // 2048 quads per row
constexpr int QPAD = QROW + 8;   // gather may read up to 8 quads past Qneed

// Canonical GCN wave64 inclusive add-scan via DPP (VALU pipe, no LDS).
__device__ __forceinline__ float wave_scan_incl(float x) {
    float f = x;
    {
        int t_ = __builtin_amdgcn_update_dpp(0, __float_as_int(f), 0x111, 0xf, 0xf, false);
        f += __int_as_float(t_);
    }
    {
        int t_ = __builtin_amdgcn_update_dpp(0, __float_as_int(f), 0x112, 0xf, 0xf, false);
        f += __int_as_float(t_);
    }
    {
        int t_ = __builtin_amdgcn_update_dpp(0, __float_as_int(f), 0x114, 0xf, 0xf, false);
        f += __int_as_float(t_);
    }
    {
        int t_ = __builtin_amdgcn_update_dpp(0, __float_as_int(f), 0x118, 0xf, 0xf, false);
        f += __int_as_float(t_);
    }
    {
        int t_ = __builtin_amdgcn_update_dpp(0, __float_as_int(f), 0x142, 0xa, 0xf, false);
        f += __int_as_float(t_);
    }
    {
        int t_ = __builtin_amdgcn_update_dpp(0, __float_as_int(f), 0x143, 0xc, 0xf, false);
        f += __int_as_float(t_);
    }
    return f;
}

__device__ __forceinline__ void stage_quad(const float* gsrc, float* lds_wave_base) {
    // dest = lds_wave_base + lane*16 (HW rule); gsrc is per-lane.
    __builtin_amdgcn_global_load_lds(
        (const __attribute__((address_space(1))) void*)gsrc,
        (__attribute__((address_space(3))) void*)lds_wave_base,
        16, 0, 0);
}
}

__global__ __launch_bounds__(NT, 8) void fs2_avg_kernel(
    const float* __restrict__ frame_scalar,
    const float* __restrict__ duration,
    const int* __restrict__ frame_scalar_len,
    const int* __restrict__ duration_len,
    float* __restrict__ out,
    int n_rows)
{
    __shared__ alignas(16) float s_frame[QPAD * 4];
    __shared__ alignas(16) float s_wA[NW];

    const int b = blockIdx.x;
    const int t = threadIdx.x;
    const int lane = t & 63;
    const int wid = t >> 6;

    const int dlen = duration_len[b];
    const int flen_i = frame_scalar_len[b];
    const float flen = (float)flen_i;

    const float* frow = frame_scalar + (size_t)b * TF;

    // ---- Phase A staging: first min(Qf, 512) quads, async, before the scan ----
    const int Qf = (flen_i + 3) >> 2;              // quads actually present in row
    const int chunk0 = (Qf < NT) ? Qf : NT;
    if (t < chunk0) {
        stage_quad(frow + 4 * t, &s_frame[4 * (wid * 64)]);
    }

    // Output 1: duration_len passthrough (independent; issue early)
    if (t == 0) out[(size_t)n_rows * TT + b] = (float)dlen;

    // ---- duration load (predicated) + round/clamp/mask ----
    const int j0 = t * 2;
    float2 d2 = (j0 < dlen)
        ? *reinterpret_cast<const float2*>(duration + (size_t)b * TT + j0)
        : make_float2(0.f, 0.f);
    float d0 = fmaxf(rintf(d2.x), 0.0f); if (j0 + 0 >= dlen) d0 = 0.0f;
    float d1 = fmaxf(rintf(d2.y), 0.0f); if (j0 + 1 >= dlen) d1 = 0.0f;
    const float c0 = d0, c1 = c0 + d1;

    // ---- wave64 inclusive scan of per-thread duration sums (DPP, exact ints) ----
    const float ws = wave_scan_incl(c1);
    if (lane == 63) s_wA[wid] = ws;

    __syncthreads();   // wave totals visible; also drains phase-A staging

    // ---- cross-wave base: two broadcast float4 reads + predicated adds ----
    const float4 wA0 = *reinterpret_cast<const float4*>(&s_wA[0]);
    const float4 wA1 = *reinterpret_cast<const float4*>(&s_wA[4]);
    float base = ws - c1;   // exclusive prefix within wave
    base += (wid > 0) ? wA0.x : 0.f;
    base += (wid > 1) ? wA0.y : 0.f;
    base += (wid > 2) ? wA0.z : 0.f;
    base += (wid > 3) ? wA0.w : 0.f;
    base += (wid > 4) ? wA1.x : 0.f;
    base += (wid > 5) ? wA1.y : 0.f;
    base += (wid > 6) ? wA1.z : 0.f;

    // ---- Phase B staging: remaining needed quads (block-uniform) ----
    const float total = wA0.x + wA0.y + wA0.z + wA0.w + wA1.x + wA1.y + wA1.z + wA1.w;
    const float Fneed = fminf(total, flen);        // exact int in fp32
    const int Qneed = ((int)Fneed + 3) >> 2;       // <= Qf <= 2048
    if (Qneed > NT) {
        #pragma unroll
        for (int r = 1; r < 4; ++r) {
            const int q = r * NT + t;
            if (q < Qneed) {
                stage_quad(frow + 4 * q, &s_frame[4 * (r * NT + wid * 64)]);
            }
        }
        __syncthreads();   // drain phase-B staging
    }

    // ---- clipped token boundaries (integers in fp32, exact) ----
    const float sprev0 = (j0 == 0) ? 0.0f : fminf(base, flen);
    const float e0 = fminf(base + c0, flen);
    const float e1 = fminf(base + c1, flen);

    const int si = (int)sprev0;
    const int mi = (int)e0;
    const int ei = (int)e1;

    // ---- direct masked summation over <=9 aligned quads, from LDS ----
    float acc0 = 0.0f, accT = 0.0f;
    if (ei > si) {
        const int q0 = si >> 2;
        {   // j = 0: only quad where p >= si can fail
            const float4 v = *reinterpret_cast<const float4*>(&s_frame[4 * q0]);
            const int p0 = 4 * q0;
            #pragma unroll
            for (int e = 0; e < 4; ++e) {
                const float x = (&v.x)[e];
                const int p = p0 + e;
                const bool ge = (p >= si);
                accT += (ge & (p < ei)) ? x : 0.f;
                acc0 += (ge & (p < mi)) ? x : 0.f;
            }
        }
        #pragma unroll
        for (int j = 1; j < 9; ++j) {
            const int q = q0 + j;
            const float4 v = *reinterpret_cast<const float4*>(&s_frame[4 * q]);
            const int p0 = 4 * q;
            #pragma unroll
            for (int e = 0; e < 4; ++e) {
                const float x = (&v.x)[e];
                const int p = p0 + e;
                accT += (p < ei) ? x : 0.f;   // p >= si guaranteed for j >= 1
                acc0 += (p < mi) ? x : 0.f;   // mi <= ei
            }
        }
    }

    const float o0 = (mi > si) ? acc0 * __builtin_amdgcn_rcpf(e0 - sprev0) : 0.0f;
    const float o1 = (ei > mi) ? (accT - acc0) * __builtin_amdgcn_rcpf(e1 - e0) : 0.0f;

    *reinterpret_cast<float2*>(out + (size_t)b * TT + j0) = make_float2(o0, o1);
}

extern "C" void kernel_launch(void* const* d_in, const int* in_sizes, int n_in,
                              void* d_out, int out_size, void* d_ws, size_t ws_size,
                              hipStream_t stream) {
    const float* frame_scalar     = (const float*)d_in[0];
    const float* duration         = (const float*)d_in[1];
    const int*   frame_scalar_len = (const int*)d_in[2];
    const int*   duration_len     = (const int*)d_in[3];
    float* out = (float*)d_out;
    const int B = in_sizes[2];   // frame_scalar_len has B elements
    fs2_avg_kernel<<<B, NT, 0, stream>>>(frame_scalar, duration, frame_scalar_len,
                                         duration_len, out, B);
}

// Round 3
// 14.926 us; speedup vs baseline: 1.0799x; 1.0799x over previous
//
#include <hip/hip_runtime.h>

// FastSpeech2 hard duration-based frame->token averaging.
// R11: replace the per-token frame GATHER (R8: 9x divergent global_load_dwordx4,
// ~64 line-requests each -> ~15us of TCP address serialization; R10: LDS variant
// hit 32-way-pattern bank conflicts + exposed staging latency) with a block-wide
// PREFIX SUM of the frame row in LDS + 2-point difference per token (exactly the
// reference's cfs[e]-cfs[s] formulation):
//  - each thread owns 16 contiguous frames: 4x float4 coalesced loads
//    (predicated at flen), 15-add local inclusive prefix
//  - second DPP wave-scan (frame totals) shares the duration scan's barrier
//  - prefix written to LDS via 4x ds_write_b128 into an XOR-swizzled layout
//    (quad-level qi ^ ((qi>>3)&7): 16B-aligned, baseline-even bank spread for
//    both the stride-64B writes and the random 3-point reads)
//  - per token: 3 predicated ds_read_b32 (boundaries shared between tokens)
// Output = [B*TT token_scalar | B duration_len(float)].

namespace {
constexpr int TT = 1024;   // tokens per row
constexpr int TF = 8192;   // frames per row
constexpr int NT = 512;    // threads per block (8 waves)
constexpr int NW = NT / 64;

// Canonical GCN wave64 inclusive add-scan via DPP (VALU pipe, no LDS).
__device__ __forceinline__ float wave_scan_incl(float x) {
    float f = x;
    {
        int t_ = __builtin_amdgcn_update_dpp(0, __float_as_int(f), 0x111, 0xf, 0xf, false);
        f += __int_as_float(t_);
    }
    {
        int t_ = __builtin_amdgcn_update_dpp(0, __float_as_int(f), 0x112, 0xf, 0xf, false);
        f += __int_as_float(t_);
    }
    {
        int t_ = __builtin_amdgcn_update_dpp(0, __float_as_int(f), 0x114, 0xf, 0xf, false);
        f += __int_as_float(t_);
    }
    {
        int t_ = __builtin_amdgcn_update_dpp(0, __float_as_int(f), 0x118, 0xf, 0xf, false);
        f += __int_as_float(t_);
    }
    {
        int t_ = __builtin_amdgcn_update_dpp(0, __float_as_int(f), 0x142, 0xa, 0xf, false);
        f += __int_as_float(t_);
    }
    {
        int t_ = __builtin_amdgcn_update_dpp(0, __float_as_int(f), 0x143, 0xc, 0xf, false);
        f += __int_as_float(t_);
    }
    return f;
}

// LDS swizzle on dword index: XOR quad bits 0-2 with bits 3-5. Bijective within
// each 64-quad block, preserves 16B alignment of quads.
__device__ __forceinline__ int swz(int i) {
    const int qi = i >> 2;
    const int q2 = qi ^ ((qi >> 3) & 7);
    return (q2 << 2) | (i & 3);
}
}

__global__ __launch_bounds__(NT, 8) void fs2_avg_kernel(
    const float* __restrict__ frame_scalar,
    const float* __restrict__ duration,
    const int* __restrict__ frame_scalar_len,
    const int* __restrict__ duration_len,
    float* __restrict__ out,
    int n_rows)
{
    __shared__ alignas(16) float s_S[TF];   // swizzled inclusive prefix: S[i] = cfs[i+1]
    __shared__ alignas(16) float s_wA[NW];  // duration wave totals
    __shared__ alignas(16) float s_wF[NW];  // frame wave totals

    const int b = blockIdx.x;
    const int t = threadIdx.x;
    const int lane = t & 63;
    const int wid = t >> 6;

    const int dlen = duration_len[b];
    const int flen_i = frame_scalar_len[b];
    const float flen = (float)flen_i;

    const float* frow = frame_scalar + (size_t)b * TF;

    // Output 1: duration_len passthrough (independent; issue early)
    if (t == 0) out[(size_t)n_rows * TT + b] = (float)dlen;

    // ---- frame chunk load: thread owns frames [16t, 16t+16) ----
    // Predicated per quad at flen (pure BW saving; row is always 8192 floats).
    // Skipped quads contribute garbage only to prefix positions >= flen, which
    // are never read.
    const int fb_idx = t * 16;
    float f[16];
    #pragma unroll
    for (int j = 0; j < 4; ++j) {
        float4 v = make_float4(0.f, 0.f, 0.f, 0.f);
        if (fb_idx + 4 * j < flen_i)
            v = *reinterpret_cast<const float4*>(frow + fb_idx + 4 * j);
        f[4 * j + 0] = v.x; f[4 * j + 1] = v.y;
        f[4 * j + 2] = v.z; f[4 * j + 3] = v.w;
    }
    // in-place local inclusive prefix
    #pragma unroll
    for (int k = 1; k < 16; ++k) f[k] += f[k - 1];
    const float ftot = f[15];

    // ---- duration load (predicated) + round/clamp/mask ----
    const int j0 = t * 2;
    float2 d2 = (j0 < dlen)
        ? *reinterpret_cast<const float2*>(duration + (size_t)b * TT + j0)
        : make_float2(0.f, 0.f);
    float d0 = fmaxf(rintf(d2.x), 0.0f); if (j0 + 0 >= dlen) d0 = 0.0f;
    float d1 = fmaxf(rintf(d2.y), 0.0f); if (j0 + 1 >= dlen) d1 = 0.0f;
    const float c0 = d0, c1 = c0 + d1;

    // ---- two independent wave64 inclusive scans (DPP, VALU pipe) ----
    const float ws  = wave_scan_incl(c1);    // durations
    const float fsc = wave_scan_incl(ftot);  // frame chunk totals
    if (lane == 63) { s_wA[wid] = ws; s_wF[wid] = fsc; }

    __syncthreads();   // barrier #1: wave totals visible

    // ---- cross-wave bases: broadcast float4 reads + predicated adds ----
    const float4 wA0 = *reinterpret_cast<const float4*>(&s_wA[0]);
    const float4 wA1 = *reinterpret_cast<const float4*>(&s_wA[4]);
    float base = ws - c1;   // exclusive duration prefix within wave
    base += (wid > 0) ? wA0.x : 0.f;
    base += (wid > 1) ? wA0.y : 0.f;
    base += (wid > 2) ? wA0.z : 0.f;
    base += (wid > 3) ? wA0.w : 0.f;
    base += (wid > 4) ? wA1.x : 0.f;
    base += (wid > 5) ? wA1.y : 0.f;
    base += (wid > 6) ? wA1.z : 0.f;

    const float4 wF0 = *reinterpret_cast<const float4*>(&s_wF[0]);
    const float4 wF1 = *reinterpret_cast<const float4*>(&s_wF[4]);
    float fbase = fsc - ftot;  // exclusive frame prefix within wave
    fbase += (wid > 0) ? wF0.x : 0.f;
    fbase += (wid > 1) ? wF0.y : 0.f;
    fbase += (wid > 2) ? wF0.z : 0.f;
    fbase += (wid > 3) ? wF0.w : 0.f;
    fbase += (wid > 4) ? wF1.x : 0.f;
    fbase += (wid > 5) ? wF1.y : 0.f;
    fbase += (wid > 6) ? wF1.z : 0.f;

    // ---- write inclusive prefix S[i] = cfs[i+1] to swizzled LDS ----
    #pragma unroll
    for (int j = 0; j < 4; ++j) {
        const int i0 = fb_idx + 4 * j;
        const float4 v = make_float4(fbase + f[4 * j + 0], fbase + f[4 * j + 1],
                                     fbase + f[4 * j + 2], fbase + f[4 * j + 3]);
        *reinterpret_cast<float4*>(&s_S[swz(i0)]) = v;
    }

    __syncthreads();   // barrier #2: prefix visible

    // ---- clipped token boundaries (integers in fp32, exact) ----
    const float sprev0 = (j0 == 0) ? 0.0f : fminf(base, flen);
    const float e0 = fminf(base + c0, flen);
    const float e1 = fminf(base + c1, flen);

    const int si = (int)sprev0;
    const int mi = (int)e0;
    const int ei = (int)e1;

    // ---- 3-point gather from prefix: seg_sum = G(e) - G(s) ----
    float o0 = 0.0f, o1 = 0.0f;
    if (ei > si) {
        const float Gs = (si == 0) ? 0.0f : s_S[swz(si - 1)];
        const float Gm = (mi == 0) ? 0.0f : s_S[swz(mi - 1)];
        const float Ge = s_S[swz(ei - 1)];           // ei > si >= 0 -> ei >= 1
        o0 = (mi > si) ? (Gm - Gs) * __builtin_amdgcn_rcpf(e0 - sprev0) : 0.0f;
        o1 = (ei > mi) ? (Ge - Gm) * __builtin_amdgcn_rcpf(e1 - e0) : 0.0f;
    }

    *reinterpret_cast<float2*>(out + (size_t)b * TT + j0) = make_float2(o0, o1);
}

extern "C" void kernel_launch(void* const* d_in, const int* in_sizes, int n_in,
                              void* d_out, int out_size, void* d_ws, size_t ws_size,
                              hipStream_t stream) {
    const float* frame_scalar     = (const float*)d_in[0];
    const float* duration         = (const float*)d_in[1];
    const int*   frame_scalar_len = (const int*)d_in[2];
    const int*   duration_len     = (const int*)d_in[3];
    float* out = (float*)d_out;
    const int B = in_sizes[2];   // frame_scalar_len has B elements
    fs2_avg_kernel<<<B, NT, 0, stream>>>(frame_scalar, duration, frame_scalar_len,
                                         duration_len, out, B);
}

// Round 4
// 14.308 us; speedup vs baseline: 1.1266x; 1.0432x over previous
//
#include <hip/hip_runtime.h>

// FastSpeech2 hard duration-based frame->token averaging.
// R12: prefix-sum algorithm (R11) with BOTH remaining inefficiencies removed:
//  - COALESCED frame loads: wave w owns quads [256w,256w+256); instr j loads
//    quad 256w+64j+lane -> lanes contiguous, 16 line-requests/instr (R11 had
//    64-B lane stride -> 64 lines/instr, same address cost as R8's gathers).
//  - Per-chunk prefix: 4 independent DPP wave-scans over per-lane quad sums,
//    chunk totals via v_readlane(63), chunk bases as wave-uniform adds,
//    cross-wave bases via the existing s_wF pass. No LDS redistribution.
//  - Final prefix written ds_write_b128 LANE-CONTIGUOUS into LINEAR LDS
//    (conflict-free, no swizzle); per-token 3-point random b32 reads.
//  - __launch_bounds__(512, 6): 85-VGPR cap (est. ~50 live) -> spill-proof,
//    occupancy stays LDS-limited at 4 blocks/CU (32 waves).
// Output = [B*TT token_scalar | B duration_len(float)].

namespace {
constexpr int TT = 1024;   // tokens per row
constexpr int TF = 8192;   // frames per row
constexpr int NT = 512;    // threads per block (8 waves)
constexpr int NW = NT / 64;

// Canonical GCN wave64 inclusive add-scan via DPP (VALU pipe, no LDS).
__device__ __forceinline__ float wave_scan_incl(float x) {
    float f = x;
    {
        int t_ = __builtin_amdgcn_update_dpp(0, __float_as_int(f), 0x111, 0xf, 0xf, false);
        f += __int_as_float(t_);
    }
    {
        int t_ = __builtin_amdgcn_update_dpp(0, __float_as_int(f), 0x112, 0xf, 0xf, false);
        f += __int_as_float(t_);
    }
    {
        int t_ = __builtin_amdgcn_update_dpp(0, __float_as_int(f), 0x114, 0xf, 0xf, false);
        f += __int_as_float(t_);
    }
    {
        int t_ = __builtin_amdgcn_update_dpp(0, __float_as_int(f), 0x118, 0xf, 0xf, false);
        f += __int_as_float(t_);
    }
    {
        int t_ = __builtin_amdgcn_update_dpp(0, __float_as_int(f), 0x142, 0xa, 0xf, false);
        f += __int_as_float(t_);
    }
    {
        int t_ = __builtin_amdgcn_update_dpp(0, __float_as_int(f), 0x143, 0xc, 0xf, false);
        f += __int_as_float(t_);
    }
    return f;
}

__device__ __forceinline__ float readlane63(float x) {
    return __int_as_float(__builtin_amdgcn_readlane(__float_as_int(x), 63));
}
}

__global__ __launch_bounds__(NT, 6) void fs2_avg_kernel(
    const float* __restrict__ frame_scalar,
    const float* __restrict__ duration,
    const int* __restrict__ frame_scalar_len,
    const int* __restrict__ duration_len,
    float* __restrict__ out,
    int n_rows)
{
    __shared__ alignas(16) float s_S[TF];   // linear inclusive prefix: S[i] = cfs[i+1]
    __shared__ alignas(16) float s_wA[NW];  // duration wave totals
    __shared__ alignas(16) float s_wF[NW];  // frame wave totals

    const int b = blockIdx.x;
    const int t = threadIdx.x;
    const int lane = t & 63;
    const int wid = t >> 6;

    const int dlen = duration_len[b];
    const int flen_i = frame_scalar_len[b];
    const float flen = (float)flen_i;

    const float* frow = frame_scalar + (size_t)b * TF;

    // Output 1: duration_len passthrough (independent; issue early)
    if (t == 0) out[(size_t)n_rows * TT + b] = (float)dlen;

    // ---- duration load FIRST (oldest outstanding -> usable while frame
    //      loads are still in flight) ----
    const int j0 = t * 2;
    float2 d2 = (j0 < dlen)
        ? *reinterpret_cast<const float2*>(duration + (size_t)b * TT + j0)
        : make_float2(0.f, 0.f);

    // ---- coalesced frame loads: wave-chunk ownership ----
    const int qb = 256 * wid + lane;        // quad index for j=0
    float4 v0 = make_float4(0.f, 0.f, 0.f, 0.f);
    float4 v1 = v0, v2 = v0, v3 = v0;
    if (4 * (qb)       < flen_i) v0 = *reinterpret_cast<const float4*>(frow + 4 * (qb));
    if (4 * (qb + 64)  < flen_i) v1 = *reinterpret_cast<const float4*>(frow + 4 * (qb + 64));
    if (4 * (qb + 128) < flen_i) v2 = *reinterpret_cast<const float4*>(frow + 4 * (qb + 128));
    if (4 * (qb + 192) < flen_i) v3 = *reinterpret_cast<const float4*>(frow + 4 * (qb + 192));

    // ---- duration round/clamp/mask (overlaps frame-load latency) ----
    float d0 = fmaxf(rintf(d2.x), 0.0f);
    float d1 = fmaxf(rintf(d2.y), 0.0f);
    if (j0 + 1 >= dlen) d1 = 0.0f;   // also covers j0 >= dlen (d2 = 0 anyway)
    const float c0 = d0, c1 = c0 + d1;

    // ---- per-quad inclusive prefixes (in regs) ----
    float p0[4], p1[4], p2[4], p3[4];
    p0[0] = v0.x; p0[1] = p0[0] + v0.y; p0[2] = p0[1] + v0.z; p0[3] = p0[2] + v0.w;
    p1[0] = v1.x; p1[1] = p1[0] + v1.y; p1[2] = p1[1] + v1.z; p1[3] = p1[2] + v1.w;
    p2[0] = v2.x; p2[1] = p2[0] + v2.y; p2[2] = p2[1] + v2.z; p2[3] = p2[2] + v2.w;
    p3[0] = v3.x; p3[1] = p3[0] + v3.y; p3[2] = p3[1] + v3.z; p3[3] = p3[2] + v3.w;

    // ---- 5 independent wave64 inclusive scans (DPP, VALU pipe, good ILP) ----
    const float ws  = wave_scan_incl(c1);     // durations
    const float f0s = wave_scan_incl(p0[3]);  // chunk j=0 quad sums
    const float f1s = wave_scan_incl(p1[3]);
    const float f2s = wave_scan_incl(p2[3]);
    const float f3s = wave_scan_incl(p3[3]);

    // chunk totals (wave-uniform) and within-wave chunk bases
    const float T0 = readlane63(f0s);
    const float T1 = readlane63(f1s);
    const float T2 = readlane63(f2s);
    const float T3 = readlane63(f3s);
    const float C1 = T0, C2 = T0 + T1, C3 = C2 + T2;
    const float Fw = C3 + T3;               // wave frame total

    if (lane == 63) { s_wA[wid] = ws; s_wF[wid] = Fw; }

    __syncthreads();   // barrier #1: wave totals visible (also drains loads)

    // ---- cross-wave bases: broadcast float4 reads + predicated adds ----
    const float4 wA0 = *reinterpret_cast<const float4*>(&s_wA[0]);
    const float4 wA1 = *reinterpret_cast<const float4*>(&s_wA[4]);
    float base = ws - c1;   // exclusive duration prefix within wave
    base += (wid > 0) ? wA0.x : 0.f;
    base += (wid > 1) ? wA0.y : 0.f;
    base += (wid > 2) ? wA0.z : 0.f;
    base += (wid > 3) ? wA0.w : 0.f;
    base += (wid > 4) ? wA1.x : 0.f;
    base += (wid > 5) ? wA1.y : 0.f;
    base += (wid > 6) ? wA1.z : 0.f;

    const float4 wF0 = *reinterpret_cast<const float4*>(&s_wF[0]);
    const float4 wF1 = *reinterpret_cast<const float4*>(&s_wF[4]);
    float FB = 0.0f;        // sum of prior waves' frame totals
    FB += (wid > 0) ? wF0.x : 0.f;
    FB += (wid > 1) ? wF0.y : 0.f;
    FB += (wid > 2) ? wF0.z : 0.f;
    FB += (wid > 3) ? wF0.w : 0.f;
    FB += (wid > 4) ? wF1.x : 0.f;
    FB += (wid > 5) ? wF1.y : 0.f;
    FB += (wid > 6) ? wF1.z : 0.f;

    // ---- final inclusive prefix -> linear LDS, lane-contiguous b128 writes ----
    {
        const float eb0 = FB      + (f0s - p0[3]);
        const float eb1 = FB + C1 + (f1s - p1[3]);
        const float eb2 = FB + C2 + (f2s - p2[3]);
        const float eb3 = FB + C3 + (f3s - p3[3]);
        *reinterpret_cast<float4*>(&s_S[4 * (qb)]) =
            make_float4(eb0 + p0[0], eb0 + p0[1], eb0 + p0[2], eb0 + p0[3]);
        *reinterpret_cast<float4*>(&s_S[4 * (qb + 64)]) =
            make_float4(eb1 + p1[0], eb1 + p1[1], eb1 + p1[2], eb1 + p1[3]);
        *reinterpret_cast<float4*>(&s_S[4 * (qb + 128)]) =
            make_float4(eb2 + p2[0], eb2 + p2[1], eb2 + p2[2], eb2 + p2[3]);
        *reinterpret_cast<float4*>(&s_S[4 * (qb + 192)]) =
            make_float4(eb3 + p3[0], eb3 + p3[1], eb3 + p3[2], eb3 + p3[3]);
    }

    __syncthreads();   // barrier #2: prefix visible

    // ---- clipped token boundaries (integers in fp32, exact) ----
    const float sprev0 = (j0 == 0) ? 0.0f : fminf(base, flen);
    const float e0 = fminf(base + c0, flen);
    const float e1 = fminf(base + c1, flen);

    const int si = (int)sprev0;
    const int mi = (int)e0;
    const int ei = (int)e1;

    // ---- 3-point gather from prefix: seg_sum = G(e) - G(s) ----
    float o0 = 0.0f, o1 = 0.0f;
    if (ei > si) {
        const float Gs = (si == 0) ? 0.0f : s_S[si - 1];
        const float Gm = (mi == 0) ? 0.0f : s_S[mi - 1];
        const float Ge = s_S[ei - 1];            // ei > si >= 0 -> ei >= 1
        o0 = (mi > si) ? (Gm - Gs) * __builtin_amdgcn_rcpf(e0 - sprev0) : 0.0f;
        o1 = (ei > mi) ? (Ge - Gm) * __builtin_amdgcn_rcpf(e1 - e0) : 0.0f;
    }

    *reinterpret_cast<float2*>(out + (size_t)b * TT + j0) = make_float2(o0, o1);
}

extern "C" void kernel_launch(void* const* d_in, const int* in_sizes, int n_in,
                              void* d_out, int out_size, void* d_ws, size_t ws_size,
                              hipStream_t stream) {
    const float* frame_scalar     = (const float*)d_in[0];
    const float* duration         = (const float*)d_in[1];
    const int*   frame_scalar_len = (const int*)d_in[2];
    const int*   duration_len     = (const int*)d_in[3];
    float* out = (float*)d_out;
    const int B = in_sizes[2];   // frame_scalar_len has B elements
    fs2_avg_kernel<<<B, NT, 0, stream>>>(frame_scalar, duration, frame_scalar_len,
                                         duration_len, out, B);
}

// Round 5
// 12.995 us; speedup vs baseline: 1.2404x; 1.1010x over previous
//
#include <hip/hip_runtime.h>

// FastSpeech2 hard duration-based frame->token averaging.
// R13 = R12 (coalesced loads + reg prefix + linear LDS) + frame-traffic cut:
//  - dur phase FIRST: scan + barrier #1 gives total = sum(dur) -> frame loads
//    predicated at Fneed = min(total, flen) instead of flen. E[min(8*dlen,
//    flen)] ~ 2731 vs E[flen] = 4096: ~33% less frame traffic (~25% total).
//    R8..R12 all pinned at 14.1-14.9us across four different inner structures
//    -> traffic (not divergence/conflicts/occupancy) is the remaining lever.
//  - barrier count stays 2: LDS prefix is WAVE-LOCAL (no cross-wave FB term);
//    the gather adds FBc(idx>>10) from the 8 wave totals via predicated adds.
//  - correctness of partial loads: any read position < Fneed <= flen depends
//    only on quads < Qneed (all loaded); garbage (beyond flen / beyond Fneed)
//    only reaches prefix positions that are never read.
// Output = [B*TT token_scalar | B duration_len(float)].

namespace {
constexpr int TT = 1024;   // tokens per row
constexpr int TF = 8192;   // frames per row
constexpr int NT = 512;    // threads per block (8 waves)
constexpr int NW = NT / 64;

// Canonical GCN wave64 inclusive add-scan via DPP (VALU pipe, no LDS).
__device__ __forceinline__ float wave_scan_incl(float x) {
    float f = x;
    {
        int t_ = __builtin_amdgcn_update_dpp(0, __float_as_int(f), 0x111, 0xf, 0xf, false);
        f += __int_as_float(t_);
    }
    {
        int t_ = __builtin_amdgcn_update_dpp(0, __float_as_int(f), 0x112, 0xf, 0xf, false);
        f += __int_as_float(t_);
    }
    {
        int t_ = __builtin_amdgcn_update_dpp(0, __float_as_int(f), 0x114, 0xf, 0xf, false);
        f += __int_as_float(t_);
    }
    {
        int t_ = __builtin_amdgcn_update_dpp(0, __float_as_int(f), 0x118, 0xf, 0xf, false);
        f += __int_as_float(t_);
    }
    {
        int t_ = __builtin_amdgcn_update_dpp(0, __float_as_int(f), 0x142, 0xa, 0xf, false);
        f += __int_as_float(t_);
    }
    {
        int t_ = __builtin_amdgcn_update_dpp(0, __float_as_int(f), 0x143, 0xc, 0xf, false);
        f += __int_as_float(t_);
    }
    return f;
}

__device__ __forceinline__ float readlane63(float x) {
    return __int_as_float(__builtin_amdgcn_readlane(__float_as_int(x), 63));
}
}

__global__ __launch_bounds__(NT, 8) void fs2_avg_kernel(
    const float* __restrict__ frame_scalar,
    const float* __restrict__ duration,
    const int* __restrict__ frame_scalar_len,
    const int* __restrict__ duration_len,
    float* __restrict__ out,
    int n_rows)
{
    __shared__ alignas(16) float s_S[TF];   // wave-local inclusive prefix
    __shared__ alignas(16) float s_wA[NW];  // duration wave totals
    __shared__ alignas(16) float s_wF[NW];  // frame wave totals

    const int b = blockIdx.x;
    const int t = threadIdx.x;
    const int lane = t & 63;
    const int wid = t >> 6;

    const int dlen = duration_len[b];
    const int flen_i = frame_scalar_len[b];
    const float flen = (float)flen_i;

    const float* frow = frame_scalar + (size_t)b * TF;

    // Output 1: duration_len passthrough (independent; issue early)
    if (t == 0) out[(size_t)n_rows * TT + b] = (float)dlen;

    // ---- duration load (predicated) + round/clamp/mask ----
    const int j0 = t * 2;
    float2 d2 = (j0 < dlen)
        ? *reinterpret_cast<const float2*>(duration + (size_t)b * TT + j0)
        : make_float2(0.f, 0.f);
    float d0 = fmaxf(rintf(d2.x), 0.0f);
    float d1 = fmaxf(rintf(d2.y), 0.0f);
    if (j0 + 1 >= dlen) d1 = 0.0f;   // covers j0 >= dlen too (d2 = 0 there)
    const float c0 = d0, c1 = c0 + d1;

    // ---- duration wave scan ----
    const float ws = wave_scan_incl(c1);
    if (lane == 63) s_wA[wid] = ws;

    __syncthreads();   // barrier #1: duration wave totals visible

    // ---- cross-wave duration base + block total ----
    const float4 wA0 = *reinterpret_cast<const float4*>(&s_wA[0]);
    const float4 wA1 = *reinterpret_cast<const float4*>(&s_wA[4]);
    float base = ws - c1;   // exclusive duration prefix within wave
    base += (wid > 0) ? wA0.x : 0.f;
    base += (wid > 1) ? wA0.y : 0.f;
    base += (wid > 2) ? wA0.z : 0.f;
    base += (wid > 3) ? wA0.w : 0.f;
    base += (wid > 4) ? wA1.x : 0.f;
    base += (wid > 5) ? wA1.y : 0.f;
    base += (wid > 6) ? wA1.z : 0.f;

    const float total = wA0.x + wA0.y + wA0.z + wA0.w
                      + wA1.x + wA1.y + wA1.z + wA1.w;
    const int Fneed_i = (int)fminf(total, flen);   // frames actually consumed

    // ---- coalesced frame loads, predicated at Fneed (the traffic cut) ----
    const int qb = 256 * wid + lane;        // quad index for j=0
    float4 v0 = make_float4(0.f, 0.f, 0.f, 0.f);
    float4 v1 = v0, v2 = v0, v3 = v0;
    if (4 * (qb)       < Fneed_i) v0 = *reinterpret_cast<const float4*>(frow + 4 * (qb));
    if (4 * (qb + 64)  < Fneed_i) v1 = *reinterpret_cast<const float4*>(frow + 4 * (qb + 64));
    if (4 * (qb + 128) < Fneed_i) v2 = *reinterpret_cast<const float4*>(frow + 4 * (qb + 128));
    if (4 * (qb + 192) < Fneed_i) v3 = *reinterpret_cast<const float4*>(frow + 4 * (qb + 192));

    // ---- token boundaries (VALU, overlaps frame-load latency) ----
    const float sprev0 = (j0 == 0) ? 0.0f : fminf(base, flen);
    const float e0 = fminf(base + c0, flen);
    const float e1 = fminf(base + c1, flen);
    const int si = (int)sprev0;
    const int mi = (int)e0;
    const int ei = (int)e1;

    // ---- per-quad inclusive prefixes (in regs) ----
    float p0[4], p1[4], p2[4], p3[4];
    p0[0] = v0.x; p0[1] = p0[0] + v0.y; p0[2] = p0[1] + v0.z; p0[3] = p0[2] + v0.w;
    p1[0] = v1.x; p1[1] = p1[0] + v1.y; p1[2] = p1[1] + v1.z; p1[3] = p1[2] + v1.w;
    p2[0] = v2.x; p2[1] = p2[0] + v2.y; p2[2] = p2[1] + v2.z; p2[3] = p2[2] + v2.w;
    p3[0] = v3.x; p3[1] = p3[0] + v3.y; p3[2] = p3[1] + v3.z; p3[3] = p3[2] + v3.w;

    // ---- 4 independent wave64 scans over quad sums (DPP, good ILP) ----
    const float f0s = wave_scan_incl(p0[3]);
    const float f1s = wave_scan_incl(p1[3]);
    const float f2s = wave_scan_incl(p2[3]);
    const float f3s = wave_scan_incl(p3[3]);

    const float T0 = readlane63(f0s);
    const float T1 = readlane63(f1s);
    const float T2 = readlane63(f2s);
    const float T3 = readlane63(f3s);
    const float Cc1 = T0, Cc2 = T0 + T1, Cc3 = Cc2 + T2;
    const float Fw = Cc3 + T3;              // wave frame total

    // ---- WAVE-LOCAL inclusive prefix -> linear LDS (lane-contiguous b128) ----
    {
        const float eb0 =       (f0s - p0[3]);
        const float eb1 = Cc1 + (f1s - p1[3]);
        const float eb2 = Cc2 + (f2s - p2[3]);
        const float eb3 = Cc3 + (f3s - p3[3]);
        *reinterpret_cast<float4*>(&s_S[4 * (qb)]) =
            make_float4(eb0 + p0[0], eb0 + p0[1], eb0 + p0[2], eb0 + p0[3]);
        *reinterpret_cast<float4*>(&s_S[4 * (qb + 64)]) =
            make_float4(eb1 + p1[0], eb1 + p1[1], eb1 + p1[2], eb1 + p1[3]);
        *reinterpret_cast<float4*>(&s_S[4 * (qb + 128)]) =
            make_float4(eb2 + p2[0], eb2 + p2[1], eb2 + p2[2], eb2 + p2[3]);
        *reinterpret_cast<float4*>(&s_S[4 * (qb + 192)]) =
            make_float4(eb3 + p3[0], eb3 + p3[1], eb3 + p3[2], eb3 + p3[3]);
    }
    if (lane == 63) s_wF[wid] = Fw;

    __syncthreads();   // barrier #2: prefix + frame wave totals visible

    // ---- gather with cross-wave correction FBc(owning wave) ----
    const float4 wF0 = *reinterpret_cast<const float4*>(&s_wF[0]);
    const float4 wF1 = *reinterpret_cast<const float4*>(&s_wF[4]);

    float o0 = 0.0f, o1 = 0.0f;
    if (ei > si) {
        auto G = [&](int idx) -> float {   // idx >= 1 guaranteed by callers
            const int i = idx - 1;
            const int w = i >> 10;         // 1024 frames per wave chunk
            float s = s_S[i];
            s += (w > 0) ? wF0.x : 0.f;
            s += (w > 1) ? wF0.y : 0.f;
            s += (w > 2) ? wF0.z : 0.f;
            s += (w > 3) ? wF0.w : 0.f;
            s += (w > 4) ? wF1.x : 0.f;
            s += (w > 5) ? wF1.y : 0.f;
            s += (w > 6) ? wF1.z : 0.f;
            return s;
        };
        const float Gs = (si == 0) ? 0.0f : G(si);
        const float Gm = (mi == 0) ? 0.0f : G(mi);
        const float Ge = G(ei);             // ei > si >= 0 -> ei >= 1
        o0 = (mi > si) ? (Gm - Gs) * __builtin_amdgcn_rcpf(e0 - sprev0) : 0.0f;
        o1 = (ei > mi) ? (Ge - Gm) * __builtin_amdgcn_rcpf(e1 - e0) : 0.0f;
    }

    *reinterpret_cast<float2*>(out + (size_t)b * TT + j0) = make_float2(o0, o1);
}

extern "C" void kernel_launch(void* const* d_in, const int* in_sizes, int n_in,
                              void* d_out, int out_size, void* d_ws, size_t ws_size,
                              hipStream_t stream) {
    const float* frame_scalar     = (const float*)d_in[0];
    const float* duration         = (const float*)d_in[1];
    const int*   frame_scalar_len = (const int*)d_in[2];
    const int*   duration_len     = (const int*)d_in[3];
    float* out = (float*)d_out;
    const int B = in_sizes[2];   // frame_scalar_len has B elements
    fs2_avg_kernel<<<B, NT, 0, stream>>>(frame_scalar, duration, frame_scalar_len,
                                         duration_len, out, B);
}